// Round 3
// baseline (844.273 us; speedup 1.0000x reference)
//
#include <hip/hip_runtime.h>
#include <math.h>

// ---- ws layout (float-slot offsets) ----
#define WS_CB     0         // 192
#define WS_QE1    192       // 16384
#define WS_XE1    16576     // 65536
#define WS_G      82112     // 65536
#define WS_HW     147648    // 266240
#define WS_U16    413888    // 8192 u32 (U rows x 32 half2)
#define WS_WHH16  422080    // 6144 u32
#define WS_W2M16  428224    // 6144 u32
#define WS_I16    434368    // 8192 u32 (unused by kA now)
#define WS_GFLAG  442560    // 256 u32

typedef _Float16 h2 __attribute__((ext_vector_type(2)));

#if defined(__has_builtin)
#if __has_builtin(__builtin_amdgcn_fdot2)
#define FDOT2(a,b,c) __builtin_amdgcn_fdot2((a),(b),(c),false)
#endif
#endif
#ifndef FDOT2
__device__ inline float fdot2_sw(h2 a, h2 b, float c){ return c + (float)a[0]*(float)b[0] + (float)a[1]*(float)b[1]; }
#define FDOT2(a,b,c) fdot2_sw((a),(b),(c))
#endif

__device__ inline h2 H2(unsigned u){ union{unsigned x; h2 h;} v; v.x=u; return v.h; }
__device__ inline unsigned short F2H(float f){ union{_Float16 h; unsigned short s;} v; v.h=(_Float16)f; return v.s; }
__device__ inline unsigned PACK2(float a, float b){ return (unsigned)F2H(a) | ((unsigned)F2H(b)<<16); }

// busy-poll LDS flag (workgroup scope, acquire)
#define SPIN(p,tgt) while (__hip_atomic_load((p), __ATOMIC_ACQUIRE, __HIP_MEMORY_SCOPE_WORKGROUP) < (tgt)) {}
#define WGREL(p,v)  __hip_atomic_store((p), (v), __ATOMIC_RELEASE, __HIP_MEMORY_SCOPE_WORKGROUP)

// ================= precompute (unchanged from v2) =================
__global__ __launch_bounds__(256) void kPrep(
    const int* __restrict__ q, const int* __restrict__ r,
    const float* __restrict__ x_emb, const float* __restrict__ q_emb,
    const float* __restrict__ init_h, const float* __restrict__ w1,
    const float* __restrict__ b1, const float* __restrict__ w2,
    const float* __restrict__ b2, const float* __restrict__ w_ih,
    const float* __restrict__ w_hh, const float* __restrict__ b_ih,
    float* __restrict__ ws, float* __restrict__ h_full)
{
  int idx = blockIdx.x*256 + threadIdx.x;
  unsigned* wsu = (unsigned*)ws;
  if (idx < 192) {
    int g = idx; float s = b_ih[g];
    for (int j=0;j<64;j++) s += b2[j]*w_ih[g*128+j];
    ws[WS_CB+g] = s;
  } else if (idx < 16576) {
    int e = idx-192; int c = e>>6, i = e&63;
    float s = b1[i];
    for (int k=0;k<64;k++) s += q_emb[c*64+k]*w1[(64+k)*64+i];
    ws[WS_QE1+e] = s;
  } else if (idx < 82112) {
    int e = idx-16576; int bt = e>>6, i = e&63;
    int row = q[bt] + 256*r[bt];
    float s = b1[i];
    for (int k=0;k<64;k++) s += x_emb[row*64+k]*w1[(64+k)*64+i];
    ws[WS_XE1+e] = s;
  } else if (idx < 147648) {
    int e = idx-82112; int a = e>>8, cc = e&255;
    float s = 0.f;
    for (int d=0;d<64;d++) s += q_emb[a*64+d]*q_emb[cc*64+d];
    ws[WS_G+e] = s;
  } else if (idx < 409792) {
    int e = idx-147648; int bb = e>>14, cf = e&16383;
    h_full[(size_t)bb*65*16384 + cf] = init_h[cf];
  } else if (idx < 417984) {
    int e = idx-409792; int rr = e>>5, d = e&31;
    float v0, v1;
    if (rr < 64) { v0 = w1[(2*d)*64+rr];   v1 = w1[(2*d+1)*64+rr]; }
    else { int g = rr-64; v0 = w_ih[g*128+64+2*d]; v1 = w_ih[g*128+64+2*d+1]; }
    wsu[WS_U16+e] = PACK2(v0,v1);
  } else if (idx < 424128) {
    int e = idx-417984; int g = e>>5, d = e&31;
    wsu[WS_WHH16+e] = PACK2(w_hh[g*64+2*d], w_hh[g*64+2*d+1]);
  } else if (idx < 430272) {
    int e = idx-424128; int g = e>>5, d = e&31;
    float s0=0.f, s1=0.f;
    for (int j=0;j<64;j++){ float wij = w_ih[g*128+j]; s0 += w2[(2*d)*64+j]*wij; s1 += w2[(2*d+1)*64+j]*wij; }
    wsu[WS_W2M16+e] = PACK2(s0,s1);
  }
}

// ================= wavefront recurrence v3 =================
// 256 WGs x 512 threads. b = bid&15, tg = bid>>4. Chains t = 4*tg + i, i=0..3.
// waves 0-3: crit (GRU). waves 4-7: helper (gi precompute + I/O).
// Weight regs per wave <= 160 h2 -> ~190 VGPR, resident at 2 waves/SIMD.
__global__ __launch_bounds__(512,2) void kA(
    const int* __restrict__ q, const float* __restrict__ b_hh,
    float* __restrict__ ws, float* __restrict__ h_full)
{
  __shared__ __align__(16) unsigned short h16s[4][16][64];  // f16 h rings
  __shared__ __align__(16) unsigned short inbox[16][64];    // chain-0 rows
  __shared__ __align__(16) unsigned short a16s[4][8][64];   // relu(m1) rings
  __shared__ float h32s[4][8][64];                          // f32 h rings
  __shared__ __align__(16) float4 gi4s[4][4][64];           // gi partials
  __shared__ int flgH[4], p2s[4];

  const int bid = blockIdx.x, b = bid & 15, tg = bid >> 4;
  const int tid = threadIdx.x, w = tid >> 6, lane = tid & 63;
  const bool isA = (w < 4);
  const int i = isA ? w : (w - 4);
  const int t = tg*4 + i;

  const unsigned* U16  = (const unsigned*)ws + WS_U16;
  const unsigned* WH16 = (const unsigned*)ws + WS_WHH16;
  const unsigned* WM16 = (const unsigned*)ws + WS_W2M16;
  const float* qe1 = ws + WS_QE1;
  const float* xe1 = ws + WS_XE1;
  const float* cb  = ws + WS_CB;
  unsigned* gflag = (unsigned*)ws + WS_GFLAG;
  unsigned* hfu = (unsigned*)h_full;

  if (tid < 4) { flgH[tid] = 0; p2s[tid] = 0; }
  if (isA) h16s[i][15][lane] = 0;   // h(-1) = 0
  __syncthreads();

  if (isA) {
    // ---- crit wave: gh dots + a.W2m_{r,z} + gates ----
    h2 wr[32], wz[32], wn[32], m2r[32], m2z[32];
    #pragma unroll
    for (int d=0; d<32; d++) {
      wr[d]  = H2(WH16[(lane)*32+d]);
      wz[d]  = H2(WH16[(64+lane)*32+d]);
      wn[d]  = H2(WH16[(128+lane)*32+d]);
      m2r[d] = H2(WM16[(lane)*32+d]);
      m2z[d] = H2(WM16[(64+lane)*32+d]);
    }
    const float bhr = b_hh[lane], bhz = b_hh[64+lane], bhn = b_hh[128+lane];
    float hreg = 0.f;

    for (int c=0; c<256; c++) {
      if (((c&3)==0) && i<3) { SPIN(&p2s[i+1], c-12); }   // h16 ring reuse (batched)
      SPIN(&p2s[i], c+1);                                  // gi[c] + a16[c] ready
      float4 gv = gi4s[i][c&3][lane];
      float g2r = 0.f, g2z = 0.f;
      {
        const uint4* ap = (const uint4*)a16s[i][c&7];
        #pragma unroll
        for (int k=0;k<8;k++){ uint4 c4 = ap[k];
          h2 p0=H2(c4.x), p1=H2(c4.y), p2=H2(c4.z), p3=H2(c4.w);
          g2r=FDOT2(m2r[4*k+0],p0,g2r); g2r=FDOT2(m2r[4*k+1],p1,g2r); g2r=FDOT2(m2r[4*k+2],p2,g2r); g2r=FDOT2(m2r[4*k+3],p3,g2r);
          g2z=FDOT2(m2z[4*k+0],p0,g2z); g2z=FDOT2(m2z[4*k+1],p1,g2z); g2z=FDOT2(m2z[4*k+2],p2,g2z); g2z=FDOT2(m2z[4*k+3],p3,g2z);
        }
      }
      float ghr = bhr, ghz = bhz, ghn = bhn;
      {
        const uint4* hp = (const uint4*)h16s[i][(c+15)&15];
        #pragma unroll
        for (int k=0;k<8;k++){ uint4 c4 = hp[k];
          h2 p0=H2(c4.x), p1=H2(c4.y), p2=H2(c4.z), p3=H2(c4.w);
          ghr=FDOT2(wr[4*k+0],p0,ghr); ghr=FDOT2(wr[4*k+1],p1,ghr); ghr=FDOT2(wr[4*k+2],p2,ghr); ghr=FDOT2(wr[4*k+3],p3,ghr);
          ghz=FDOT2(wz[4*k+0],p0,ghz); ghz=FDOT2(wz[4*k+1],p1,ghz); ghz=FDOT2(wz[4*k+2],p2,ghz); ghz=FDOT2(wz[4*k+3],p3,ghz);
          ghn=FDOT2(wn[4*k+0],p0,ghn); ghn=FDOT2(wn[4*k+1],p1,ghn); ghn=FDOT2(wn[4*k+2],p2,ghn); ghn=FDOT2(wn[4*k+3],p3,ghn);
        }
      }
      float rg = 1.f/(1.f+__expf(-(gv.x + g2r + ghr)));
      float zg = 1.f/(1.f+__expf(-(gv.y + g2z + ghz)));
      float xn = gv.z + rg*ghn;
      float e2 = __expf(2.f*xn);
      float ng = 1.f - 2.f/(e2+1.f);
      hreg = zg*hreg + (1.f-zg)*ng;
      h16s[i][c&15][lane] = F2H(hreg);
      h32s[i][c&7][lane]  = hreg;
      if (lane == 0) WGREL(&flgH[i], c+1);
    }
  } else {
    // ---- helper wave: U-dots (phase1) + a.W2m_n (phase2, lag 1) + I/O ----
    h2 u0[32],u1[32],u2[32],u3[32],w2n[32];
    #pragma unroll
    for (int d=0; d<32; d++) {
      u0[d]  = H2(U16[(lane)*32+d]);
      u1[d]  = H2(U16[(64+lane)*32+d]);
      u2[d]  = H2(U16[(128+lane)*32+d]);
      u3[d]  = H2(U16[(192+lane)*32+d]);
      w2n[d] = H2(WM16[(128+lane)*32+d]);
    }
    const float cbr = cb[lane], cbz = cb[64+lane], cbn = cb[128+lane];
    const int qrow = q[b*64+t];
    const float xr = xe1[(b*64+t)*64+lane];
    const unsigned* hfp = hfu + (size_t)(b*65 + 4*tg)*16384;
    float*    hfoF = h_full + (size_t)(b*65 + t + 1)*16384;
    unsigned* hfoU = hfu + (size_t)(b*65 + t + 1)*16384;
    unsigned* gfp = gflag + (b*16 + tg - 1);
    unsigned* gfc = gflag + (b*16 + tg);
    const bool needFlag = (i==3) && (tg < 15);
    unsigned gv = 0;

    if (i == 0) {   // preload inbox rows 0..3
      if (tg > 0) {
        while ((gv = __hip_atomic_load(gfp, __ATOMIC_RELAXED, __HIP_MEMORY_SCOPE_AGENT)) < 4u)
          __builtin_amdgcn_s_sleep(1);
      }
      for (int rr=0; rr<4; rr++) {
        union{unsigned u; float f;} cv;
        cv.u = __hip_atomic_load(&hfp[rr*64+lane], __ATOMIC_RELAXED, __HIP_MEMORY_SCOPE_AGENT);
        inbox[rr][lane] = F2H(cv.f);
      }
    }
    float e1cur = (qrow == 0) ? xr : qe1[lane];
    float prP=0.f, pzP=0.f, pnP=0.f;

    for (int s=0; s<=260; s++) {
      int tgt = s-4; if (tgt > 256) tgt = 256;
      SPIN(&flgH[i], tgt);          // rings: a16(s-8), gi(s-5), h32 row (s-5)
      float vrow = 0.f;
      const bool havePf = (i==0) && (s+4 <= 255);
      if (havePf) {
        if (tg > 0) {
          while (gv < (unsigned)(s+5)) {
            gv = __hip_atomic_load(gfp, __ATOMIC_RELAXED, __HIP_MEMORY_SCOPE_AGENT);
            if (gv < (unsigned)(s+5)) __builtin_amdgcn_s_sleep(1);
          }
        }
        union{unsigned u; float f;} cv;
        cv.u = __hip_atomic_load(&hfp[(s+4)*64+lane], __ATOMIC_RELAXED, __HIP_MEMORY_SCOPE_AGENT);
        vrow = cv.f;
      }
      float pr=0.f, pz=0.f, pn=0.f;
      if (s <= 255) {
        if (i > 0) { SPIN(&flgH[i-1], s+1); }
        const uint4* rp = (const uint4*)((i==0) ? inbox[s&15] : h16s[i-1][s&15]);
        float m1 = e1cur; pr = cbr; pz = cbz; pn = cbn;
        #pragma unroll
        for (int k=0;k<8;k++){ uint4 c4 = rp[k];
          h2 p0=H2(c4.x), p1=H2(c4.y), p2=H2(c4.z), p3=H2(c4.w);
          m1=FDOT2(u0[4*k+0],p0,m1); m1=FDOT2(u0[4*k+1],p1,m1); m1=FDOT2(u0[4*k+2],p2,m1); m1=FDOT2(u0[4*k+3],p3,m1);
          pr=FDOT2(u1[4*k+0],p0,pr); pr=FDOT2(u1[4*k+1],p1,pr); pr=FDOT2(u1[4*k+2],p2,pr); pr=FDOT2(u1[4*k+3],p3,pr);
          pz=FDOT2(u2[4*k+0],p0,pz); pz=FDOT2(u2[4*k+1],p1,pz); pz=FDOT2(u2[4*k+2],p2,pz); pz=FDOT2(u2[4*k+3],p3,pz);
          pn=FDOT2(u3[4*k+0],p0,pn); pn=FDOT2(u3[4*k+1],p1,pn); pn=FDOT2(u3[4*k+2],p2,pn); pn=FDOT2(u3[4*k+3],p3,pn);
        }
        float av = fmaxf(m1, 0.f);
        a16s[i][s&7][lane] = F2H(av);
      }
      if (s >= 1 && s <= 256) {
        int sm = s-1;
        float g2n = 0.f;
        const uint4* ap = (const uint4*)a16s[i][sm&7];
        #pragma unroll
        for (int k=0;k<8;k++){ uint4 c4 = ap[k];
          g2n=FDOT2(w2n[4*k+0],H2(c4.x),g2n); g2n=FDOT2(w2n[4*k+1],H2(c4.y),g2n);
          g2n=FDOT2(w2n[4*k+2],H2(c4.z),g2n); g2n=FDOT2(w2n[4*k+3],H2(c4.w),g2n);
        }
        gi4s[i][sm&3][lane] = make_float4(prP, pzP, pnP + g2n, 0.f);
      }
      if (s <= 255) { prP = pr; pzP = pz; pnP = pn; }
      int r = s-5;
      if (r >= 0) {           // copyout row r (flgH >= r+1 guaranteed by top spin)
        float hv = h32s[i][r&7][lane];
        if (i == 3) {
          union{float f; unsigned u;} cu; cu.f = hv;
          __hip_atomic_store(&hfoU[r*64+lane], cu.u, __ATOMIC_RELAXED, __HIP_MEMORY_SCOPE_AGENT);
        } else {
          hfoF[r*64+lane] = hv;
        }
        if (needFlag && ((r&3)==3)) {
          asm volatile("s_waitcnt vmcnt(0)" ::: "memory");
          if (lane == 0) __hip_atomic_store(gfc, (unsigned)(r+1), __ATOMIC_RELAXED, __HIP_MEMORY_SCOPE_AGENT);
        }
      }
      if (havePf) inbox[(s+4)&15][lane] = F2H(vrow);
      if (lane == 0) WGREL(&p2s[i], s);
      if (s < 255) e1cur = ((s+1) == qrow) ? xr : qe1[(s+1)*64+lane];
    }
  }
}

// ================= hw[b][u][c] = h_full[b][u][c][:] . out_w =================
__global__ __launch_bounds__(256) void kHw(const float* __restrict__ h_full,
    const float* __restrict__ out_w, float* __restrict__ hw)
{
  __shared__ float ow[64];
  if (threadIdx.x < 64) ow[threadIdx.x] = out_w[threadIdx.x];
  __syncthreads();
  const int blk = blockIdx.x, c = threadIdx.x;
  const float* hp = h_full + ((size_t)blk*256 + c)*64;
  float s = 0.f;
  #pragma unroll
  for (int f=0; f<64; f++) s += hp[f]*ow[f];
  hw[blk*256+c] = s;
}

// ================= readout =================
__global__ __launch_bounds__(256) void kY(const int* __restrict__ q,
    const float* __restrict__ ws, const float* __restrict__ bias,
    const float* __restrict__ theta, float* __restrict__ y)
{
  const float* G  = ws + WS_G;
  const float* hw = ws + WS_HW;
  const int b = blockIdx.x >> 2, tq = blockIdx.x & 3;
  const int c = threadIdx.x;
  __shared__ float siml[64][256];
  for (int u=0; u<64; u++) {
    int qq = q[b*64+u];
    siml[u][c] = G[qq*256+c];
  }
  __syncthreads();
  const float rate = __expf(theta[0]);
  const float bv = bias[c];
  const float* hwb = hw + b*65*256;
  for (int tt=0; tt<16; tt++) {
    const int t = tq*16+tt;
    float mx = -1e30f;
    for (int u=0; u<=t; u++) {
      float s = __expf(-rate*(float)(t-u))*siml[u][c];
      mx = fmaxf(mx, s);
    }
    float se = 0.f, sw = 0.f;
    for (int u=0; u<=t; u++) {
      float s = __expf(-rate*(float)(t-u))*siml[u][c];
      float e = __expf(s-mx);
      se += e; sw += e*hwb[u*256+c];
    }
    float lg = hwb[(t+1)*256+c] + sw/se + bv;
    y[(b*64+t)*256+c] = 1.f/(1.f+__expf(-lg));
  }
}

extern "C" void kernel_launch(void* const* d_in, const int* in_sizes, int n_in,
                              void* d_out, int out_size, void* d_ws, size_t ws_size,
                              hipStream_t stream)
{
  (void)in_sizes; (void)n_in; (void)out_size; (void)ws_size;
  const int*   q      = (const int*)  d_in[0];
  const int*   r      = (const int*)  d_in[1];
  const float* x_emb  = (const float*)d_in[2];
  const float* q_emb  = (const float*)d_in[3];
  const float* init_h = (const float*)d_in[4];
  const float* w1     = (const float*)d_in[5];
  const float* b1     = (const float*)d_in[6];
  const float* w2     = (const float*)d_in[7];
  const float* b2     = (const float*)d_in[8];
  const float* w_ih   = (const float*)d_in[9];
  const float* w_hh   = (const float*)d_in[10];
  const float* b_ih   = (const float*)d_in[11];
  const float* b_hh   = (const float*)d_in[12];
  const float* bias   = (const float*)d_in[13];
  const float* out_w  = (const float*)d_in[14];
  const float* theta  = (const float*)d_in[15];

  float* out    = (float*)d_out;
  float* y      = out;
  float* h_full = out + 262144;
  float* ws     = (float*)d_ws;

  hipMemsetAsync((unsigned*)ws + WS_GFLAG, 0, 256*sizeof(unsigned), stream);
  kPrep<<<1681,256,0,stream>>>(q,r,x_emb,q_emb,init_h,w1,b1,w2,b2,w_ih,w_hh,b_ih,ws,h_full);
  {
    void* ka[] = { (void*)&q, (void*)&b_hh, (void*)&ws, (void*)&h_full };
    hipError_t e = hipLaunchCooperativeKernel((const void*)kA, dim3(256), dim3(512), ka, 0, stream);
    if (e != hipSuccess) {
      kA<<<dim3(256),dim3(512),0,stream>>>(q,b_hh,ws,h_full);
    }
  }
  kHw<<<1040,256,0,stream>>>(h_full, out_w, ws + WS_HW);
  kY<<<64,256,0,stream>>>(q, ws, bias, theta, y);
}

// Round 4
// 795.795 us; speedup vs baseline: 1.0609x; 1.0609x over previous
//
#include <hip/hip_runtime.h>
#include <math.h>

// ---- ws layout (float-slot offsets) ----
#define WS_CB     0         // 192
#define WS_QE1    192       // 16384
#define WS_XE1    16576     // 65536
#define WS_G      82112     // 65536
#define WS_HW     147648    // 266240
#define WS_U16    413888    // 8192 u32
#define WS_WHH16  422080    // 6144 u32
#define WS_W2M16  428224    // 6144 u32
#define WS_GFLAG  442560    // 256 u32

typedef _Float16 h2 __attribute__((ext_vector_type(2)));

#if defined(__has_builtin)
#if __has_builtin(__builtin_amdgcn_fdot2)
#define FDOT2(a,b,c) __builtin_amdgcn_fdot2((a),(b),(c),false)
#endif
#endif
#ifndef FDOT2
__device__ inline float fdot2_sw(h2 a, h2 b, float c){ return c + (float)a[0]*(float)b[0] + (float)a[1]*(float)b[1]; }
#define FDOT2(a,b,c) fdot2_sw((a),(b),(c))
#endif

__device__ inline h2 H2(unsigned u){ union{unsigned x; h2 h;} v; v.x=u; return v.h; }
__device__ inline unsigned short F2H(float f){ union{_Float16 h; unsigned short s;} v; v.h=(_Float16)f; return v.s; }
__device__ inline unsigned PACK2(float a, float b){ return (unsigned)F2H(a) | ((unsigned)F2H(b)<<16); }

// ---- named-register forcing machinery ----
#define F32(X,A) X(A,0)X(A,1)X(A,2)X(A,3)X(A,4)X(A,5)X(A,6)X(A,7)X(A,8)X(A,9)X(A,10)X(A,11)X(A,12)X(A,13)X(A,14)X(A,15)X(A,16)X(A,17)X(A,18)X(A,19)X(A,20)X(A,21)X(A,22)X(A,23)X(A,24)X(A,25)X(A,26)X(A,27)X(A,28)X(A,29)X(A,30)X(A,31)
#define DCL1(W,K) h2 W##_##K;
#define DECLW(W) F32(DCL1,W)
#define LD1(W,K) W##_##K = H2(_wb[K]);
#define LOADW(W,BASE) { const unsigned* _wb=(BASE); F32(LD1,W) }
#define DT1(W,K) _acc = FDOT2(W##_##K, H2(RC##K), _acc);
#define DOTW(ACC,W) { float _acc=(ACC); F32(DT1,W) (ACC)=_acc; }
#define RC0 qq0.x
#define RC1 qq0.y
#define RC2 qq0.z
#define RC3 qq0.w
#define RC4 qq1.x
#define RC5 qq1.y
#define RC6 qq1.z
#define RC7 qq1.w
#define RC8 qq2.x
#define RC9 qq2.y
#define RC10 qq2.z
#define RC11 qq2.w
#define RC12 qq3.x
#define RC13 qq3.y
#define RC14 qq3.z
#define RC15 qq3.w
#define RC16 qq4.x
#define RC17 qq4.y
#define RC18 qq4.z
#define RC19 qq4.w
#define RC20 qq5.x
#define RC21 qq5.y
#define RC22 qq5.z
#define RC23 qq5.w
#define RC24 qq6.x
#define RC25 qq6.y
#define RC26 qq6.z
#define RC27 qq6.w
#define RC28 qq7.x
#define RC29 qq7.y
#define RC30 qq7.z
#define RC31 qq7.w
#define LOADROW(P) { const uint4* _rp=(const uint4*)(P); qq0=_rp[0];qq1=_rp[1];qq2=_rp[2];qq3=_rp[3];qq4=_rp[4];qq5=_rp[5];qq6=_rp[6];qq7=_rp[7]; }

// plain volatile LDS flag poll (DS ops are per-wave in-order; no cache ops)
#define POLLGE(F,T) do{ while(*(volatile int*)&(F) < (T)) {} asm volatile("" ::: "memory"); }while(0)

// ================= precompute =================
__global__ __launch_bounds__(256) void kPrep(
    const int* __restrict__ q, const int* __restrict__ r,
    const float* __restrict__ x_emb, const float* __restrict__ q_emb,
    const float* __restrict__ init_h, const float* __restrict__ w1,
    const float* __restrict__ b1, const float* __restrict__ w2,
    const float* __restrict__ b2, const float* __restrict__ w_ih,
    const float* __restrict__ w_hh, const float* __restrict__ b_ih,
    float* __restrict__ ws, float* __restrict__ h_full)
{
  int idx = blockIdx.x*256 + threadIdx.x;
  unsigned* wsu = (unsigned*)ws;
  if (idx < 192) {
    int g = idx; float s = b_ih[g];
    for (int j=0;j<64;j++) s += b2[j]*w_ih[g*128+j];
    ws[WS_CB+g] = s;
  } else if (idx < 16576) {
    int e = idx-192; int c = e>>6, i = e&63;
    float s = b1[i];
    for (int k=0;k<64;k++) s += q_emb[c*64+k]*w1[(64+k)*64+i];
    ws[WS_QE1+e] = s;
  } else if (idx < 82112) {
    int e = idx-16576; int bt = e>>6, i = e&63;
    int row = q[bt] + 256*r[bt];
    float s = b1[i];
    for (int k=0;k<64;k++) s += x_emb[row*64+k]*w1[(64+k)*64+i];
    ws[WS_XE1+e] = s;
  } else if (idx < 147648) {
    int e = idx-82112; int a = e>>8, cc = e&255;
    float s = 0.f;
    for (int d=0;d<64;d++) s += q_emb[a*64+d]*q_emb[cc*64+d];
    ws[WS_G+e] = s;
  } else if (idx < 409792) {
    int e = idx-147648; int bb = e>>14, cf = e&16383;
    h_full[(size_t)bb*65*16384 + cf] = init_h[cf];
  } else if (idx < 417984) {
    int e = idx-409792; int rr = e>>5, d = e&31;
    float v0, v1;
    if (rr < 64) { v0 = w1[(2*d)*64+rr];   v1 = w1[(2*d+1)*64+rr]; }
    else { int g = rr-64; v0 = w_ih[g*128+64+2*d]; v1 = w_ih[g*128+64+2*d+1]; }
    wsu[WS_U16+e] = PACK2(v0,v1);
  } else if (idx < 424128) {
    int e = idx-417984; int g = e>>5, d = e&31;
    wsu[WS_WHH16+e] = PACK2(w_hh[g*64+2*d], w_hh[g*64+2*d+1]);
  } else if (idx < 430272) {
    int e = idx-424128; int g = e>>5, d = e&31;
    float s0=0.f, s1=0.f;
    for (int j=0;j<64;j++){ float wij = w_ih[g*128+j]; s0 += w2[(2*d)*64+j]*wij; s1 += w2[(2*d+1)*64+j]*wij; }
    wsu[WS_W2M16+e] = PACK2(s0,s1);
  }
}

// ================= wavefront recurrence v4 =================
// 256 WGs x 512 threads. b = bid&15, tg = bid>>4. Chains t = 4*tg+i, i=0..3.
// waves 0-3: crit (GRU gates). waves 4-7: helper (U-dots + I/O).
__global__ __launch_bounds__(512,2) void kA(
    const int* __restrict__ q, const float* __restrict__ b_hh,
    float* __restrict__ ws, float* __restrict__ h_full)
{
  __shared__ __align__(16) unsigned short h16s[4][16][64];
  __shared__ __align__(16) unsigned short a16s[4][8][64];
  __shared__ __align__(16) unsigned short inbox[16][64];
  __shared__ __align__(16) float4 gi4s[4][8][64];
  __shared__ float h32s[4][8][64];
  __shared__ int flgH[4], p2s[4], ioPr[4];

  const int bid=blockIdx.x, b=bid&15, tg=bid>>4;
  const int tid=threadIdx.x, w=tid>>6, lane=tid&63;
  const bool isA = (w<4);
  const int i = isA? w : w-4;
  const int t = tg*4 + i;

  const unsigned* U16  = (const unsigned*)ws + WS_U16;
  const unsigned* WH16 = (const unsigned*)ws + WS_WHH16;
  const unsigned* WM16 = (const unsigned*)ws + WS_W2M16;
  const float* qe1 = ws + WS_QE1;
  const float* xe1 = ws + WS_XE1;
  const float* cb  = ws + WS_CB;
  unsigned* gflag = (unsigned*)ws + WS_GFLAG;

  if (tid<4){ flgH[tid]=0; p2s[tid]=0; ioPr[tid]=0; }
  if (isA) h16s[i][15][lane]=0;   // h(-1)=0
  __syncthreads();

  uint4 qq0,qq1,qq2,qq3,qq4,qq5,qq6,qq7;

  if (isA) {
    // ---- crit wave: gh dots + a.W2m_{r,z} + gates ----
    DECLW(wrq) DECLW(wzq) DECLW(wnq) DECLW(mrq) DECLW(mzq)
    LOADW(wrq, WH16+lane*32)
    LOADW(wzq, WH16+(64+lane)*32)
    LOADW(wnq, WH16+(128+lane)*32)
    LOADW(mrq, WM16+lane*32)
    LOADW(mzq, WM16+(64+lane)*32)
    const float bhr=b_hh[lane], bhz=b_hh[64+lane], bhn=b_hh[128+lane];
    float hreg=0.f;
    for (int c=0;c<256;c++){
      if (((c&7)==0) && i<3) POLLGE(p2s[i+1], c-8);   // h16 ring reuse
      if ((c&3)==0) POLLGE(ioPr[i], c-4);             // h32 ring reuse
      LOADROW(h16s[i][(c+15)&15])                     // own row c-1 (no flag dep)
      float ghr=bhr, ghz=bhz, ghn=bhn;
      DOTW(ghr,wrq) DOTW(ghz,wzq) DOTW(ghn,wnq)
      POLLGE(p2s[i], c+1);                            // gi[c]+a16[c] ready
      float4 gv = gi4s[i][c&7][lane];
      LOADROW(a16s[i][c&7])
      float g2r=0.f, g2z=0.f;
      DOTW(g2r,mrq) DOTW(g2z,mzq)
      float rg = 1.f/(1.f+__expf(-(gv.x+g2r+ghr)));
      float zg = 1.f/(1.f+__expf(-(gv.y+g2z+ghz)));
      float xn = gv.z + rg*ghn;
      float e2 = __expf(2.f*xn);
      float ng = 1.f-2.f/(e2+1.f);
      hreg = zg*hreg + (1.f-zg)*ng;
      h16s[i][c&15][lane]=F2H(hreg);
      h32s[i][c&7][lane]=hreg;
      asm volatile("s_waitcnt lgkmcnt(0)" ::: "memory");
      if (lane==0) *(volatile int*)&flgH[i]=c+1;
    }
  } else {
    // ---- helper wave: U-dots + a.W2m_n (lag 1) + opportunistic I/O ----
    DECLW(u0q) DECLW(u1q) DECLW(u2q) DECLW(u3q) DECLW(w2q)
    LOADW(u0q, U16+lane*32)
    LOADW(u1q, U16+(64+lane)*32)
    LOADW(u2q, U16+(128+lane)*32)
    LOADW(u3q, U16+(192+lane)*32)
    LOADW(w2q, WM16+(128+lane)*32)
    const float cbr=cb[lane], cbz=cb[64+lane], cbn=cb[128+lane];
    const int qrow=q[b*64+t];
    const float xr=xe1[(b*64+t)*64+lane];
    const float* hfp = h_full + (size_t)(b*65+4*tg)*16384;
    float* hfoF = h_full + (size_t)(b*65+t+1)*16384;
    unsigned* hfoU = (unsigned*)hfoF;
    unsigned* gfp = gflag + (b*16+tg-1);
    unsigned* gfc = gflag + (b*16+tg);
    const bool pubG = (i==3) && (tg<15);
    unsigned gv=0; int pfrow=0, cp=0;
    float e1cur = (qrow==0)? xr : qe1[lane];
    float prP=0.f,pzP=0.f,pnP=0.f;

    for (int s=0;s<=256;s++){
      if ((s&3)==0) POLLGE(flgH[i], s-4);   // a16/gi ring reuse (depth 8)
      float e1n=0.f;
      if (s<255) e1n = ((s+1)==qrow)? xr : qe1[(s+1)*64+lane];
      float pr=0.f,pz=0.f,pn=0.f;
      if (s<=255){
        if (i==0){
          // blocking fill to row s, opportunistic 1 ahead (depth<=8)
          while (pfrow<=s){
            if (tg>0){
              while (gv < (unsigned)(pfrow+1)){
                gv = __hip_atomic_load(gfp,__ATOMIC_RELAXED,__HIP_MEMORY_SCOPE_AGENT);
                if (gv < (unsigned)(pfrow+1)) __builtin_amdgcn_s_sleep(1);
              }
              union{unsigned u; float f;} cv;
              cv.u = __hip_atomic_load((const unsigned*)&hfp[pfrow*64+lane],__ATOMIC_RELAXED,__HIP_MEMORY_SCOPE_AGENT);
              inbox[pfrow&15][lane]=F2H(cv.f);
            } else {
              inbox[pfrow&15][lane]=F2H(hfp[pfrow*64+lane]);
            }
            pfrow++;
          }
          if (pfrow<=s+8){
            bool can=(tg==0);
            if (tg>0){
              if (gv>=(unsigned)(pfrow+1)) can=true;
              else if ((s&1)==0){ gv=__hip_atomic_load(gfp,__ATOMIC_RELAXED,__HIP_MEMORY_SCOPE_AGENT); can = gv>=(unsigned)(pfrow+1); }
            }
            if (can){
              if (tg>0){
                union{unsigned u; float f;} cv;
                cv.u = __hip_atomic_load((const unsigned*)&hfp[pfrow*64+lane],__ATOMIC_RELAXED,__HIP_MEMORY_SCOPE_AGENT);
                inbox[pfrow&15][lane]=F2H(cv.f);
              } else {
                inbox[pfrow&15][lane]=F2H(hfp[pfrow*64+lane]);
              }
              pfrow++;
            }
          }
        } else {
          POLLGE(flgH[i-1], s+1);
        }
        LOADROW( (i==0)? inbox[s&15] : h16s[i-1][s&15] )
        float m1=e1cur; pr=cbr; pz=cbz; pn=cbn;
        DOTW(m1,u0q) DOTW(pr,u1q) DOTW(pz,u2q) DOTW(pn,u3q)
        a16s[i][s&7][lane]=F2H(fmaxf(m1,0.f));
      }
      if (s>=1){
        LOADROW(a16s[i][(s-1)&7])
        float g2n=0.f; DOTW(g2n,w2q)
        gi4s[i][(s-1)&7][lane]=make_float4(prP,pzP,pnP+g2n,0.f);
      }
      asm volatile("s_waitcnt lgkmcnt(0)" ::: "memory");
      if (lane==0) *(volatile int*)&p2s[i]=s;
      prP=pr; pzP=pz; pnP=pn; e1cur=e1n;
      // opportunistic copyout (<=2 rows/step)
      int av=*(volatile int*)&flgH[i];
      asm volatile("" ::: "memory");
      int nc=0;
      while (cp<av && nc<2){
        float hv=h32s[i][cp&7][lane];
        if (i==3){ union{float f; unsigned u;} cu; cu.f=hv;
          __hip_atomic_store(&hfoU[cp*64+lane],cu.u,__ATOMIC_RELAXED,__HIP_MEMORY_SCOPE_AGENT);
        } else hfoF[cp*64+lane]=hv;
        cp++; nc++;
        if ((cp&3)==0){
          *(volatile int*)&ioPr[i]=cp;
          if (pubG){ asm volatile("s_waitcnt vmcnt(0)" ::: "memory");
            if (lane==0) __hip_atomic_store(gfc,(unsigned)cp,__ATOMIC_RELAXED,__HIP_MEMORY_SCOPE_AGENT); }
        }
      }
    }
    // drain remaining rows
    while (cp<256){
      POLLGE(flgH[i], cp+1);
      float hv=h32s[i][cp&7][lane];
      if (i==3){ union{float f; unsigned u;} cu; cu.f=hv;
        __hip_atomic_store(&hfoU[cp*64+lane],cu.u,__ATOMIC_RELAXED,__HIP_MEMORY_SCOPE_AGENT);
      } else hfoF[cp*64+lane]=hv;
      cp++;
      if ((cp&3)==0){
        *(volatile int*)&ioPr[i]=cp;
        if (pubG){ asm volatile("s_waitcnt vmcnt(0)" ::: "memory");
          if (lane==0) __hip_atomic_store(gfc,(unsigned)cp,__ATOMIC_RELAXED,__HIP_MEMORY_SCOPE_AGENT); }
      }
    }
  }
}

// ================= hw[b][u][c] = h_full[b][u][c][:] . out_w =================
__global__ __launch_bounds__(256) void kHw(const float* __restrict__ h_full,
    const float* __restrict__ out_w, float* __restrict__ hw)
{
  __shared__ float ow[64];
  if (threadIdx.x < 64) ow[threadIdx.x] = out_w[threadIdx.x];
  __syncthreads();
  const int blk = blockIdx.x, c = threadIdx.x;
  const float* hp = h_full + ((size_t)blk*256 + c)*64;
  float s = 0.f;
  #pragma unroll
  for (int f=0; f<64; f++) s += hp[f]*ow[f];
  hw[blk*256+c] = s;
}

// ================= readout =================
__global__ __launch_bounds__(256) void kY(const int* __restrict__ q,
    const float* __restrict__ ws, const float* __restrict__ bias,
    const float* __restrict__ theta, float* __restrict__ y)
{
  const float* G  = ws + WS_G;
  const float* hw = ws + WS_HW;
  const int b = blockIdx.x >> 2, tq = blockIdx.x & 3;
  const int c = threadIdx.x;
  __shared__ float siml[64][256];
  for (int u=0; u<64; u++) {
    int qq = q[b*64+u];
    siml[u][c] = G[qq*256+c];
  }
  __syncthreads();
  const float rate = __expf(theta[0]);
  const float bv = bias[c];
  const float* hwb = hw + b*65*256;
  for (int tt=0; tt<16; tt++) {
    const int t = tq*16+tt;
    float mx = -1e30f;
    for (int u=0; u<=t; u++) {
      float s = __expf(-rate*(float)(t-u))*siml[u][c];
      mx = fmaxf(mx, s);
    }
    float se = 0.f, sw = 0.f;
    for (int u=0; u<=t; u++) {
      float s = __expf(-rate*(float)(t-u))*siml[u][c];
      float e = __expf(s-mx);
      se += e; sw += e*hwb[u*256+c];
    }
    float lg = hwb[(t+1)*256+c] + sw/se + bv;
    y[(b*64+t)*256+c] = 1.f/(1.f+__expf(-lg));
  }
}

extern "C" void kernel_launch(void* const* d_in, const int* in_sizes, int n_in,
                              void* d_out, int out_size, void* d_ws, size_t ws_size,
                              hipStream_t stream)
{
  (void)in_sizes; (void)n_in; (void)out_size; (void)ws_size;
  const int*   q      = (const int*)  d_in[0];
  const int*   r      = (const int*)  d_in[1];
  const float* x_emb  = (const float*)d_in[2];
  const float* q_emb  = (const float*)d_in[3];
  const float* init_h = (const float*)d_in[4];
  const float* w1     = (const float*)d_in[5];
  const float* b1     = (const float*)d_in[6];
  const float* w2     = (const float*)d_in[7];
  const float* b2     = (const float*)d_in[8];
  const float* w_ih   = (const float*)d_in[9];
  const float* w_hh   = (const float*)d_in[10];
  const float* b_ih   = (const float*)d_in[11];
  const float* b_hh   = (const float*)d_in[12];
  const float* bias   = (const float*)d_in[13];
  const float* out_w  = (const float*)d_in[14];
  const float* theta  = (const float*)d_in[15];

  float* out    = (float*)d_out;
  float* y      = out;
  float* h_full = out + 262144;
  float* ws     = (float*)d_ws;

  hipMemsetAsync((unsigned*)ws + WS_GFLAG, 0, 256*sizeof(unsigned), stream);
  kPrep<<<1681,256,0,stream>>>(q,r,x_emb,q_emb,init_h,w1,b1,w2,b2,w_ih,w_hh,b_ih,ws,h_full);
  {
    void* ka[] = { (void*)&q, (void*)&b_hh, (void*)&ws, (void*)&h_full };
    hipError_t e = hipLaunchCooperativeKernel((const void*)kA, dim3(256), dim3(512), ka, 0, stream);
    if (e != hipSuccess) {
      kA<<<dim3(256),dim3(512),0,stream>>>(q,b_hh,ws,h_full);
    }
  }
  kHw<<<1040,256,0,stream>>>(h_full, out_w, ws + WS_HW);
  kY<<<64,256,0,stream>>>(q, ws, bias, theta, y);
}

// Round 5
// 794.349 us; speedup vs baseline: 1.0628x; 1.0018x over previous
//
#include <hip/hip_runtime.h>
#include <math.h>

// ---- ws layout (float-slot offsets) ----
#define WS_CB     0         // 192
#define WS_QE1    192       // 16384
#define WS_XE1    16576     // 65536
#define WS_G      82112     // 65536
#define WS_HW     147648    // 266240
#define WS_U16    413888    // 8192 u32
#define WS_WHH16  422080    // 6144 u32
#define WS_W2M16  428224    // 6144 u32
#define WS_GFLAG  442560    // 256 u32

typedef _Float16 h2 __attribute__((ext_vector_type(2)));

#if defined(__has_builtin)
#if __has_builtin(__builtin_amdgcn_fdot2)
#define FDOT2(a,b,c) __builtin_amdgcn_fdot2((a),(b),(c),false)
#endif
#endif
#ifndef FDOT2
__device__ inline float fdot2_sw(h2 a, h2 b, float c){ return c + (float)a[0]*(float)b[0] + (float)a[1]*(float)b[1]; }
#define FDOT2(a,b,c) fdot2_sw((a),(b),(c))
#endif

__device__ inline h2 H2(unsigned u){ union{unsigned x; h2 h;} v; v.x=u; return v.h; }
__device__ inline unsigned short F2H(float f){ union{_Float16 h; unsigned short s;} v; v.h=(_Float16)f; return v.s; }
__device__ inline unsigned PACK2(float a, float b){ return (unsigned)F2H(a) | ((unsigned)F2H(b)<<16); }

// ---- named-register forcing machinery ----
#define F32(X,A) X(A,0)X(A,1)X(A,2)X(A,3)X(A,4)X(A,5)X(A,6)X(A,7)X(A,8)X(A,9)X(A,10)X(A,11)X(A,12)X(A,13)X(A,14)X(A,15)X(A,16)X(A,17)X(A,18)X(A,19)X(A,20)X(A,21)X(A,22)X(A,23)X(A,24)X(A,25)X(A,26)X(A,27)X(A,28)X(A,29)X(A,30)X(A,31)
#define DCL1(W,K) h2 W##_##K;
#define DECLW(W) F32(DCL1,W)
#define LD1(W,K) W##_##K = H2(_wb[K]);
#define LOADW(W,BASE) { const unsigned* _wb=(BASE); F32(LD1,W) }
// opaque pin: value's def becomes non-rematerializable -> must stay register-resident
#define PIN1(W,K) asm volatile("" : "+v"(W##_##K));
#define PINW(W) F32(PIN1,W)
#define DT1(W,K) _acc = FDOT2(W##_##K, H2(RC##K), _acc);
#define DOTW(ACC,W) { float _acc=(ACC); F32(DT1,W) (ACC)=_acc; }
#define RC0 qq0.x
#define RC1 qq0.y
#define RC2 qq0.z
#define RC3 qq0.w
#define RC4 qq1.x
#define RC5 qq1.y
#define RC6 qq1.z
#define RC7 qq1.w
#define RC8 qq2.x
#define RC9 qq2.y
#define RC10 qq2.z
#define RC11 qq2.w
#define RC12 qq3.x
#define RC13 qq3.y
#define RC14 qq3.z
#define RC15 qq3.w
#define RC16 qq4.x
#define RC17 qq4.y
#define RC18 qq4.z
#define RC19 qq4.w
#define RC20 qq5.x
#define RC21 qq5.y
#define RC22 qq5.z
#define RC23 qq5.w
#define RC24 qq6.x
#define RC25 qq6.y
#define RC26 qq6.z
#define RC27 qq6.w
#define RC28 qq7.x
#define RC29 qq7.y
#define RC30 qq7.z
#define RC31 qq7.w
#define LOADROW(P) { const uint4* _rp=(const uint4*)(P); qq0=_rp[0];qq1=_rp[1];qq2=_rp[2];qq3=_rp[3];qq4=_rp[4];qq5=_rp[5];qq6=_rp[6];qq7=_rp[7]; }

// plain volatile LDS flag poll (DS ops are per-wave in-order; no cache ops)
#define POLLGE(F,T) do{ while(*(volatile int*)&(F) < (T)) {} asm volatile("" ::: "memory"); }while(0)

// ================= precompute =================
__global__ __launch_bounds__(256) void kPrep(
    const int* __restrict__ q, const int* __restrict__ r,
    const float* __restrict__ x_emb, const float* __restrict__ q_emb,
    const float* __restrict__ init_h, const float* __restrict__ w1,
    const float* __restrict__ b1, const float* __restrict__ w2,
    const float* __restrict__ b2, const float* __restrict__ w_ih,
    const float* __restrict__ w_hh, const float* __restrict__ b_ih,
    float* __restrict__ ws, float* __restrict__ h_full)
{
  int idx = blockIdx.x*256 + threadIdx.x;
  unsigned* wsu = (unsigned*)ws;
  if (idx < 192) {
    int g = idx; float s = b_ih[g];
    for (int j=0;j<64;j++) s += b2[j]*w_ih[g*128+j];
    ws[WS_CB+g] = s;
  } else if (idx < 16576) {
    int e = idx-192; int c = e>>6, i = e&63;
    float s = b1[i];
    for (int k=0;k<64;k++) s += q_emb[c*64+k]*w1[(64+k)*64+i];
    ws[WS_QE1+e] = s;
  } else if (idx < 82112) {
    int e = idx-16576; int bt = e>>6, i = e&63;
    int row = q[bt] + 256*r[bt];
    float s = b1[i];
    for (int k=0;k<64;k++) s += x_emb[row*64+k]*w1[(64+k)*64+i];
    ws[WS_XE1+e] = s;
  } else if (idx < 147648) {
    int e = idx-82112; int a = e>>8, cc = e&255;
    float s = 0.f;
    for (int d=0;d<64;d++) s += q_emb[a*64+d]*q_emb[cc*64+d];
    ws[WS_G+e] = s;
  } else if (idx < 409792) {
    int e = idx-147648; int bb = e>>14, cf = e&16383;
    h_full[(size_t)bb*65*16384 + cf] = init_h[cf];
  } else if (idx < 417984) {
    int e = idx-409792; int rr = e>>5, d = e&31;
    float v0, v1;
    if (rr < 64) { v0 = w1[(2*d)*64+rr];   v1 = w1[(2*d+1)*64+rr]; }
    else { int g = rr-64; v0 = w_ih[g*128+64+2*d]; v1 = w_ih[g*128+64+2*d+1]; }
    wsu[WS_U16+e] = PACK2(v0,v1);
  } else if (idx < 424128) {
    int e = idx-417984; int g = e>>5, d = e&31;
    wsu[WS_WHH16+e] = PACK2(w_hh[g*64+2*d], w_hh[g*64+2*d+1]);
  } else if (idx < 430272) {
    int e = idx-424128; int g = e>>5, d = e&31;
    float s0=0.f, s1=0.f;
    for (int j=0;j<64;j++){ float wij = w_ih[g*128+j]; s0 += w2[(2*d)*64+j]*wij; s1 += w2[(2*d+1)*64+j]*wij; }
    wsu[WS_W2M16+e] = PACK2(s0,s1);
  }
}

// ================= wavefront recurrence v5 =================
// 256 WGs x 512 threads, 1 WG/CU (cooperative grid == CU count).
// waves_per_eu(2,2): clamp scheduler occupancy target to what actually runs
// (8 waves/CU = 2/SIMD) -> 256-VGPR budget -> weight registers stay resident.
__global__ __launch_bounds__(512) __attribute__((amdgpu_waves_per_eu(2,2)))
void kA(
    const int* __restrict__ q, const float* __restrict__ b_hh,
    float* __restrict__ ws, float* __restrict__ h_full)
{
  __shared__ __align__(16) unsigned short h16s[4][16][64];
  __shared__ __align__(16) unsigned short a16s[4][8][64];
  __shared__ __align__(16) unsigned short inbox[16][64];
  __shared__ __align__(16) float4 gi4s[4][8][64];
  __shared__ float h32s[4][8][64];
  __shared__ int flgH[4], p2s[4], ioPr[4];

  const int bid=blockIdx.x, b=bid&15, tg=bid>>4;
  const int tid=threadIdx.x, w=tid>>6, lane=tid&63;
  const bool isA = (w<4);
  const int i = isA? w : w-4;
  const int t = tg*4 + i;

  const unsigned* U16  = (const unsigned*)ws + WS_U16;
  const unsigned* WH16 = (const unsigned*)ws + WS_WHH16;
  const unsigned* WM16 = (const unsigned*)ws + WS_W2M16;
  const float* qe1 = ws + WS_QE1;
  const float* xe1 = ws + WS_XE1;
  const float* cb  = ws + WS_CB;
  unsigned* gflag = (unsigned*)ws + WS_GFLAG;

  if (tid<4){ flgH[tid]=0; p2s[tid]=0; ioPr[tid]=0; }
  if (isA) h16s[i][15][lane]=0;   // h(-1)=0
  __syncthreads();

  uint4 qq0,qq1,qq2,qq3,qq4,qq5,qq6,qq7;

  if (isA) {
    // ---- crit wave: gh dots + a.W2m_{r,z} + gates ----
    DECLW(wrq) DECLW(wzq) DECLW(wnq) DECLW(mrq) DECLW(mzq)
    LOADW(wrq, WH16+lane*32)
    LOADW(wzq, WH16+(64+lane)*32)
    LOADW(wnq, WH16+(128+lane)*32)
    LOADW(mrq, WM16+lane*32)
    LOADW(mzq, WM16+(64+lane)*32)
    PINW(wrq) PINW(wzq) PINW(wnq) PINW(mrq) PINW(mzq)
    const float bhr=b_hh[lane], bhz=b_hh[64+lane], bhn=b_hh[128+lane];
    float hreg=0.f;
    for (int c=0;c<256;c++){
      if (((c&7)==0) && i<3) POLLGE(p2s[i+1], c-8);   // h16 ring reuse
      if ((c&3)==0) POLLGE(ioPr[i], c-4);             // h32 ring reuse
      LOADROW(h16s[i][(c+15)&15])                     // own row c-1 (no flag dep)
      float ghr=bhr, ghz=bhz, ghn=bhn;
      DOTW(ghr,wrq) DOTW(ghz,wzq) DOTW(ghn,wnq)
      POLLGE(p2s[i], c+1);                            // gi[c]+a16[c] ready
      float4 gv = gi4s[i][c&7][lane];
      LOADROW(a16s[i][c&7])
      float g2r=0.f, g2z=0.f;
      DOTW(g2r,mrq) DOTW(g2z,mzq)
      float rg = 1.f/(1.f+__expf(-(gv.x+g2r+ghr)));
      float zg = 1.f/(1.f+__expf(-(gv.y+g2z+ghz)));
      float xn = gv.z + rg*ghn;
      float e2 = __expf(2.f*xn);
      float ng = 1.f-2.f/(e2+1.f);
      hreg = zg*hreg + (1.f-zg)*ng;
      h16s[i][c&15][lane]=F2H(hreg);
      h32s[i][c&7][lane]=hreg;
      asm volatile("s_waitcnt lgkmcnt(0)" ::: "memory");
      if (lane==0) *(volatile int*)&flgH[i]=c+1;
    }
  } else {
    // ---- helper wave: U-dots + a.W2m_n (lag 1) + opportunistic I/O ----
    DECLW(u0q) DECLW(u1q) DECLW(u2q) DECLW(u3q) DECLW(w2q)
    LOADW(u0q, U16+lane*32)
    LOADW(u1q, U16+(64+lane)*32)
    LOADW(u2q, U16+(128+lane)*32)
    LOADW(u3q, U16+(192+lane)*32)
    LOADW(w2q, WM16+(128+lane)*32)
    PINW(u0q) PINW(u1q) PINW(u2q) PINW(u3q) PINW(w2q)
    const float cbr=cb[lane], cbz=cb[64+lane], cbn=cb[128+lane];
    const int qrow=q[b*64+t];
    const float xr=xe1[(b*64+t)*64+lane];
    const float* hfp = h_full + (size_t)(b*65+4*tg)*16384;
    float* hfoF = h_full + (size_t)(b*65+t+1)*16384;
    unsigned* hfoU = (unsigned*)hfoF;
    unsigned* gfp = gflag + (b*16+tg-1);
    unsigned* gfc = gflag + (b*16+tg);
    const bool pubG = (i==3) && (tg<15);
    unsigned gv=0; int pfrow=0, cp=0;
    float e1cur = (qrow==0)? xr : qe1[lane];
    float prP=0.f,pzP=0.f,pnP=0.f;

    for (int s=0;s<=256;s++){
      if ((s&3)==0) POLLGE(flgH[i], s-4);   // a16/gi ring reuse (depth 8)
      float e1n=0.f;
      if (s<255) e1n = ((s+1)==qrow)? xr : qe1[(s+1)*64+lane];
      float pr=0.f,pz=0.f,pn=0.f;
      if (s<=255){
        if (i==0){
          // blocking fill to row s, opportunistic 1 ahead (depth<=8)
          while (pfrow<=s){
            if (tg>0){
              while (gv < (unsigned)(pfrow+1)){
                gv = __hip_atomic_load(gfp,__ATOMIC_RELAXED,__HIP_MEMORY_SCOPE_AGENT);
                if (gv < (unsigned)(pfrow+1)) __builtin_amdgcn_s_sleep(1);
              }
              union{unsigned u; float f;} cv;
              cv.u = __hip_atomic_load((const unsigned*)&hfp[pfrow*64+lane],__ATOMIC_RELAXED,__HIP_MEMORY_SCOPE_AGENT);
              inbox[pfrow&15][lane]=F2H(cv.f);
            } else {
              inbox[pfrow&15][lane]=F2H(hfp[pfrow*64+lane]);
            }
            pfrow++;
          }
          if (pfrow<=s+8){
            bool can=(tg==0);
            if (tg>0){
              if (gv>=(unsigned)(pfrow+1)) can=true;
              else if ((s&1)==0){ gv=__hip_atomic_load(gfp,__ATOMIC_RELAXED,__HIP_MEMORY_SCOPE_AGENT); can = gv>=(unsigned)(pfrow+1); }
            }
            if (can){
              if (tg>0){
                union{unsigned u; float f;} cv;
                cv.u = __hip_atomic_load((const unsigned*)&hfp[pfrow*64+lane],__ATOMIC_RELAXED,__HIP_MEMORY_SCOPE_AGENT);
                inbox[pfrow&15][lane]=F2H(cv.f);
              } else {
                inbox[pfrow&15][lane]=F2H(hfp[pfrow*64+lane]);
              }
              pfrow++;
            }
          }
        } else {
          POLLGE(flgH[i-1], s+1);
        }
        LOADROW( (i==0)? inbox[s&15] : h16s[i-1][s&15] )
        float m1=e1cur; pr=cbr; pz=cbz; pn=cbn;
        DOTW(m1,u0q) DOTW(pr,u1q) DOTW(pz,u2q) DOTW(pn,u3q)
        a16s[i][s&7][lane]=F2H(fmaxf(m1,0.f));
      }
      if (s>=1){
        LOADROW(a16s[i][(s-1)&7])
        float g2n=0.f; DOTW(g2n,w2q)
        gi4s[i][(s-1)&7][lane]=make_float4(prP,pzP,pnP+g2n,0.f);
      }
      asm volatile("s_waitcnt lgkmcnt(0)" ::: "memory");
      if (lane==0) *(volatile int*)&p2s[i]=s;
      prP=pr; pzP=pz; pnP=pn; e1cur=e1n;
      // opportunistic copyout (<=2 rows/step)
      int av=*(volatile int*)&flgH[i];
      asm volatile("" ::: "memory");
      int nc=0;
      while (cp<av && nc<2){
        float hv=h32s[i][cp&7][lane];
        if (i==3){ union{float f; unsigned u;} cu; cu.f=hv;
          __hip_atomic_store(&hfoU[cp*64+lane],cu.u,__ATOMIC_RELAXED,__HIP_MEMORY_SCOPE_AGENT);
        } else hfoF[cp*64+lane]=hv;
        cp++; nc++;
        if ((cp&3)==0){
          *(volatile int*)&ioPr[i]=cp;
          if (pubG){ asm volatile("s_waitcnt vmcnt(0)" ::: "memory");
            if (lane==0) __hip_atomic_store(gfc,(unsigned)cp,__ATOMIC_RELAXED,__HIP_MEMORY_SCOPE_AGENT); }
        }
      }
    }
    // drain remaining rows
    while (cp<256){
      POLLGE(flgH[i], cp+1);
      float hv=h32s[i][cp&7][lane];
      if (i==3){ union{float f; unsigned u;} cu; cu.f=hv;
        __hip_atomic_store(&hfoU[cp*64+lane],cu.u,__ATOMIC_RELAXED,__HIP_MEMORY_SCOPE_AGENT);
      } else hfoF[cp*64+lane]=hv;
      cp++;
      if ((cp&3)==0){
        *(volatile int*)&ioPr[i]=cp;
        if (pubG){ asm volatile("s_waitcnt vmcnt(0)" ::: "memory");
          if (lane==0) __hip_atomic_store(gfc,(unsigned)cp,__ATOMIC_RELAXED,__HIP_MEMORY_SCOPE_AGENT); }
      }
    }
  }
}

// ================= hw[b][u][c] = h_full[b][u][c][:] . out_w =================
__global__ __launch_bounds__(256) void kHw(const float* __restrict__ h_full,
    const float* __restrict__ out_w, float* __restrict__ hw)
{
  __shared__ float ow[64];
  if (threadIdx.x < 64) ow[threadIdx.x] = out_w[threadIdx.x];
  __syncthreads();
  const int blk = blockIdx.x, c = threadIdx.x;
  const float* hp = h_full + ((size_t)blk*256 + c)*64;
  float s = 0.f;
  #pragma unroll
  for (int f=0; f<64; f++) s += hp[f]*ow[f];
  hw[blk*256+c] = s;
}

// ================= readout =================
__global__ __launch_bounds__(256) void kY(const int* __restrict__ q,
    const float* __restrict__ ws, const float* __restrict__ bias,
    const float* __restrict__ theta, float* __restrict__ y)
{
  const float* G  = ws + WS_G;
  const float* hw = ws + WS_HW;
  const int b = blockIdx.x >> 2, tq = blockIdx.x & 3;
  const int c = threadIdx.x;
  __shared__ float siml[64][256];
  for (int u=0; u<64; u++) {
    int qq = q[b*64+u];
    siml[u][c] = G[qq*256+c];
  }
  __syncthreads();
  const float rate = __expf(theta[0]);
  const float bv = bias[c];
  const float* hwb = hw + b*65*256;
  for (int tt=0; tt<16; tt++) {
    const int t = tq*16+tt;
    float mx = -1e30f;
    for (int u=0; u<=t; u++) {
      float s = __expf(-rate*(float)(t-u))*siml[u][c];
      mx = fmaxf(mx, s);
    }
    float se = 0.f, sw = 0.f;
    for (int u=0; u<=t; u++) {
      float s = __expf(-rate*(float)(t-u))*siml[u][c];
      float e = __expf(s-mx);
      se += e; sw += e*hwb[u*256+c];
    }
    float lg = hwb[(t+1)*256+c] + sw/se + bv;
    y[(b*64+t)*256+c] = 1.f/(1.f+__expf(-lg));
  }
}

extern "C" void kernel_launch(void* const* d_in, const int* in_sizes, int n_in,
                              void* d_out, int out_size, void* d_ws, size_t ws_size,
                              hipStream_t stream)
{
  (void)in_sizes; (void)n_in; (void)out_size; (void)ws_size;
  const int*   q      = (const int*)  d_in[0];
  const int*   r      = (const int*)  d_in[1];
  const float* x_emb  = (const float*)d_in[2];
  const float* q_emb  = (const float*)d_in[3];
  const float* init_h = (const float*)d_in[4];
  const float* w1     = (const float*)d_in[5];
  const float* b1     = (const float*)d_in[6];
  const float* w2     = (const float*)d_in[7];
  const float* b2     = (const float*)d_in[8];
  const float* w_ih   = (const float*)d_in[9];
  const float* w_hh   = (const float*)d_in[10];
  const float* b_ih   = (const float*)d_in[11];
  const float* b_hh   = (const float*)d_in[12];
  const float* bias   = (const float*)d_in[13];
  const float* out_w  = (const float*)d_in[14];
  const float* theta  = (const float*)d_in[15];

  float* out    = (float*)d_out;
  float* y      = out;
  float* h_full = out + 262144;
  float* ws     = (float*)d_ws;

  hipMemsetAsync((unsigned*)ws + WS_GFLAG, 0, 256*sizeof(unsigned), stream);
  kPrep<<<1681,256,0,stream>>>(q,r,x_emb,q_emb,init_h,w1,b1,w2,b2,w_ih,w_hh,b_ih,ws,h_full);
  {
    void* ka[] = { (void*)&q, (void*)&b_hh, (void*)&ws, (void*)&h_full };
    hipError_t e = hipLaunchCooperativeKernel((const void*)kA, dim3(256), dim3(512), ka, 0, stream);
    if (e != hipSuccess) {
      kA<<<dim3(256),dim3(512),0,stream>>>(q,b_hh,ws,h_full);
    }
  }
  kHw<<<1040,256,0,stream>>>(h_full, out_w, ws + WS_HW);
  kY<<<64,256,0,stream>>>(q, ws, bias, theta, y);
}